// Round 13
// baseline (683.944 us; speedup 1.0000x reference)
//
#include <hip/hip_runtime.h>
#include <hip/hip_bf16.h>

// MHSA: B=16, C=256, H=W=48, N=2304.
// S[b,n,m] = q[b,:,n]·k[b,:,m] + rhq[b][n%48][m] + rwq[b][n/48][m]
// att = softmax_m(S); out[b,c,n] = sum_m v[b,c,m] att[n,m]
// Logits: f16 2-pass (qh·K + ql·K), K single f16 plane (R12-proven, 0.031).
//
// R13: flash split-KV. Evidence: dur == (max per-CU m-tile-units) x 5.4us;
// 288 blocks -> 32 CUs carry 72 units while 224 idle at 36 (Occ 13% decay;
// R7's balanced grid showed flat 26%). Split m-range into nsplit chunks
// (grid.z), store unnormalized partials (o bf16, (m,l) f32), tiny combine
// kernel. 72 -> 45 units (nsplit=4) / 54 (nsplit=2 fallback if ws small).
// Partial planes 0/1 alias dead xt_hi/xt_lo; 2/3 carved only if ws allows.

#define BB 16
#define CC 256
#define HH 48
#define NN 2304

typedef float f32x4 __attribute__((ext_vector_type(4)));
typedef short bf16x8 __attribute__((ext_vector_type(8)));
typedef _Float16 f16x8 __attribute__((ext_vector_type(8)));

#define MFMA(a, b, c)  __builtin_amdgcn_mfma_f32_16x16x32_bf16((a), (b), (c), 0, 0, 0)
#define MFMAH(a, b, c) __builtin_amdgcn_mfma_f32_16x16x32_f16((a), (b), (c), 0, 0, 0)

__device__ inline bf16x8 ldg8(const __hip_bfloat16* p) {
    return *reinterpret_cast<const bf16x8*>(p);
}
__device__ inline f16x8 ldh8(const _Float16* p) {
    return *reinterpret_cast<const f16x8*>(p);
}
__device__ inline float bf2f(unsigned short v) {
    unsigned u = (unsigned)v << 16;
    float f;
    __builtin_memcpy(&f, &u, 4);
    return f;
}

typedef __attribute__((address_space(3))) unsigned int lds_uint;
typedef const __attribute__((address_space(1))) unsigned int gbl_uint;

__device__ inline void gload_lds16(const void* g, void* l) {
    __builtin_amdgcn_global_load_lds((gbl_uint*)g, (lds_uint*)l, 16, 0, 0);
}

// ---- prep: transpose x [b][c][n] -> xT [b][n][c], split into bf16 hi/lo ----
__global__ __launch_bounds__(256) void k_prep_x(const float* __restrict__ x,
        __hip_bfloat16* __restrict__ xt_hi, __hip_bfloat16* __restrict__ xt_lo) {
    __shared__ float tile[64][65];
    int b = blockIdx.z, n0 = blockIdx.x * 64, c0 = blockIdx.y * 64;
    const float* xb = x + (size_t)b * CC * NN;
    #pragma unroll
    for (int i = 0; i < 16; ++i) {
        int idx = i * 256 + threadIdx.x;
        int r = idx >> 6, col = idx & 63;
        tile[r][col] = xb[(size_t)(c0 + r) * NN + n0 + col];
    }
    __syncthreads();
    #pragma unroll
    for (int i = 0; i < 16; ++i) {
        int idx = i * 256 + threadIdx.x;
        int r = idx >> 6, col = idx & 63;           // r = n-local, col = c-local
        float v = tile[col][r];
        __hip_bfloat16 h = __float2bfloat16(v);
        size_t o = ((size_t)b * NN + n0 + r) * CC + c0 + col;
        xt_hi[o] = h;
        xt_lo[o] = __float2bfloat16(v - __bfloat162float(h));
    }
}

// ---- prep: split Wq/Wk/Wv into hi/lo (layout [3][256][256] row-major) ----
__global__ __launch_bounds__(256) void k_prep_w(const float* __restrict__ Wq,
        const float* __restrict__ Wk, const float* __restrict__ Wv,
        __hip_bfloat16* __restrict__ w_hi, __hip_bfloat16* __restrict__ w_lo) {
    int i = blockIdx.x * 256 + threadIdx.x;         // < 3*65536
    int m = i >> 16, j = i & 65535;
    const float* W = (m == 0) ? Wq : ((m == 1) ? Wk : Wv);
    float v = W[j];
    __hip_bfloat16 h = __float2bfloat16(v);
    w_hi[i] = h;
    w_lo[i] = __float2bfloat16(v - __bfloat162float(h));
}

// ---- prep: relhT[h][c] = rel_h[c][h] etc, f16 hi/lo split ----
__global__ __launch_bounds__(256) void k_prep_rel(const float* __restrict__ rel_h,
        const float* __restrict__ rel_w,
        _Float16* __restrict__ relhT_hi, _Float16* __restrict__ relhT_lo,
        _Float16* __restrict__ relwT_hi, _Float16* __restrict__ relwT_lo) {
    int i = blockIdx.x * 256 + threadIdx.x;         // < 48*256
    int h = i >> 8, c = i & 255;
    float vh = rel_h[c * HH + h];
    float vw = rel_w[c * HH + h];
    _Float16 hh = (_Float16)vh;
    relhT_hi[i] = hh;
    relhT_lo[i] = (_Float16)(vh - (float)hh);
    _Float16 hw = (_Float16)vw;
    relwT_hi[i] = hw;
    relwT_lo[i] = (_Float16)(vw - (float)hw);
}

// ---- projection GEMM: yT[b][n][o] = sum_c xT[b][n][c] * W[o][c] + bias[o] ----
// pj=0 -> qT f16 hi/lo, pj=1 -> kT f16 single, pj=2 -> v[b][o][n] bf16
__global__ __launch_bounds__(256) void k_proj(
        const __hip_bfloat16* __restrict__ xt_hi, const __hip_bfloat16* __restrict__ xt_lo,
        const __hip_bfloat16* __restrict__ w_hi,  const __hip_bfloat16* __restrict__ w_lo,
        const float* __restrict__ bq, const float* __restrict__ bk, const float* __restrict__ bv,
        _Float16* __restrict__ qt_hi, _Float16* __restrict__ qt_lo,
        _Float16* __restrict__ kt,
        __hip_bfloat16* __restrict__ vbuf) {
    int b = blockIdx.y, pj = blockIdx.z;
    int n0 = (blockIdx.x >> 2) * 64, o0 = (blockIdx.x & 3) * 64;
    int wave = threadIdx.x >> 6, lane = threadIdx.x & 63;
    int lr = lane & 15, lg = lane >> 4;
    int rowA = n0 + wave * 16 + lr;
    const __hip_bfloat16* wh = w_hi + (size_t)pj * 65536;
    const __hip_bfloat16* wl = w_lo + (size_t)pj * 65536;
    const __hip_bfloat16* axh = xt_hi + ((size_t)b * NN + rowA) * CC;
    const __hip_bfloat16* axl = xt_lo + ((size_t)b * NN + rowA) * CC;
    f32x4 acc[4] = {};
    #pragma unroll
    for (int ks = 0; ks < 8; ++ks) {
        int kk = ks * 32 + lg * 8;
        bf16x8 ah = ldg8(axh + kk);
        bf16x8 al = ldg8(axl + kk);
        #pragma unroll
        for (int ot = 0; ot < 4; ++ot) {
            int rowB = o0 + ot * 16 + lr;
            bf16x8 bh = ldg8(wh + rowB * CC + kk);
            bf16x8 bl = ldg8(wl + rowB * CC + kk);
            acc[ot] = MFMA(ah, bh, acc[ot]);
            acc[ot] = MFMA(ah, bl, acc[ot]);
            acc[ot] = MFMA(al, bh, acc[ot]);
        }
    }
    const float* bias = (pj == 0) ? bq : ((pj == 1) ? bk : bv);
    #pragma unroll
    for (int ot = 0; ot < 4; ++ot) {
        int o = o0 + ot * 16 + lr;
        float bb = bias[o];
        #pragma unroll
        for (int r = 0; r < 4; ++r) {
            int n = n0 + wave * 16 + lg * 4 + r;
            float y = acc[ot][r] + bb;
            if (pj == 0) {
                _Float16 h = (_Float16)y;
                size_t off = ((size_t)b * NN + n) * CC + o;
                qt_hi[off] = h;
                qt_lo[off] = (_Float16)(y - (float)h);
            } else if (pj == 1) {
                kt[((size_t)b * NN + n) * CC + o] = (_Float16)y;
            } else {
                vbuf[((size_t)b * CC + o) * NN + n] = __float2bfloat16(y);
            }
        }
    }
}

// ---- pos rank-split (f16 3-pass): rhq[b][h][m] = sum_c relhT[h][c] q[b][c][m]
__global__ __launch_bounds__(256) void k_posq(
        const _Float16* __restrict__ qt_hi, const _Float16* __restrict__ qt_lo,
        const _Float16* __restrict__ relhT_hi, const _Float16* __restrict__ relhT_lo,
        const _Float16* __restrict__ relwT_hi, const _Float16* __restrict__ relwT_lo,
        float* __restrict__ rhq, float* __restrict__ rwq) {
    int b = blockIdx.y, m0 = blockIdx.x * 64;
    int wave = threadIdx.x >> 6, lane = threadIdx.x & 63;
    int lr = lane & 15, lg = lane >> 4;
    int m = m0 + wave * 16 + lr;                    // output column
    const size_t bN = (size_t)b * NN;
    f32x4 acc[6] = {};                              // 3 h-tiles rh, 3 w-tiles rw
    #pragma unroll
    for (int ks = 0; ks < 8; ++ks) {
        int kk = ks * 32 + lg * 8;
        f16x8 bhf = ldh8(qt_hi + (bN + m) * CC + kk);
        f16x8 blf = ldh8(qt_lo + (bN + m) * CC + kk);
        #pragma unroll
        for (int t = 0; t < 3; ++t) {
            int rowH = t * 16 + lr;
            f16x8 ahh = ldh8(relhT_hi + rowH * CC + kk);
            f16x8 ahl = ldh8(relhT_lo + rowH * CC + kk);
            acc[t] = MFMAH(ahh, bhf, acc[t]);
            acc[t] = MFMAH(ahl, bhf, acc[t]);
            acc[t] = MFMAH(ahh, blf, acc[t]);
            f16x8 awh = ldh8(relwT_hi + rowH * CC + kk);
            f16x8 awl = ldh8(relwT_lo + rowH * CC + kk);
            acc[3 + t] = MFMAH(awh, bhf, acc[3 + t]);
            acc[3 + t] = MFMAH(awl, bhf, acc[3 + t]);
            acc[3 + t] = MFMAH(awh, blf, acc[3 + t]);
        }
    }
    #pragma unroll
    for (int t = 0; t < 3; ++t) {
        #pragma unroll
        for (int r = 0; r < 4; ++r) {
            int h = t * 16 + lg * 4 + r;
            rhq[((size_t)b * HH + h) * NN + m] = acc[t][r];
            rwq[((size_t)b * HH + h) * NN + m] = acc[3 + t][r];
        }
    }
}

// ---- flash attention, split-KV: block = 128 q-rows x [t0, t0+tpb) m-tiles ----
// grid (18, 16, nsplit); z picks the m-chunk. Writes unnormalized partial o
// (bf16, plane per z) and per-row (m,l) f32. Structure otherwise R12-proven.
__global__ __launch_bounds__(512, 2) void k_attn(
        const _Float16* __restrict__ qt_hi, const _Float16* __restrict__ qt_lo,
        const _Float16* __restrict__ kt,
        const float* __restrict__ rhq, const float* __restrict__ rwq,
        const __hip_bfloat16* __restrict__ vbuf,
        __hip_bfloat16* __restrict__ o0, __hip_bfloat16* __restrict__ o1,
        __hip_bfloat16* __restrict__ o2, __hip_bfloat16* __restrict__ o3,
        float2* __restrict__ ml, int tpb) {
    __shared__ __align__(16) _Float16 lds_k[2][64][64];           // [buf][row][k] 16KB
    __shared__ __align__(16) __hip_bfloat16 lds_v[256][64];       // [c][m] 32KB (swizzled)
    __shared__ __align__(16) __hip_bfloat16 lds_p[128][64];       // shared P tile 16KB (swizzled)
    float* lds_scale = reinterpret_cast<float*>(&lds_k[1][0][0]); // dead-buf alias (R11-proven)
    int b = blockIdx.y;
    int n0 = blockIdx.x * 128;
    int z = blockIdx.z;
    int t0 = z * tpb, t_end = t0 + tpb;
    __hip_bfloat16* opart = (z == 0) ? o0 : (z == 1) ? o1 : (z == 2) ? o2 : o3;
    int wave = threadIdx.x >> 6, lane = threadIdx.x & 63;
    int lr = lane & 15, lg = lane >> 4;
    int rowA = n0 + wave * 16 + lr;
    const size_t bN = (size_t)b * NN;

    // Q fragments in registers: 16 rows x 256 k per wave, f16 hi+lo
    f16x8 qh[8], ql[8];
    #pragma unroll
    for (int ks = 0; ks < 8; ++ks) {
        int kk = ks * 32 + lg * 8;
        qh[ks] = ldh8(qt_hi + (bN + rowA) * CC + kk);
        ql[ks] = ldh8(qt_lo + (bN + rowA) * CC + kk);
    }
    // pos-table row indices for this lane's 4 softmax rows
    int hn[4], wn[4];
    #pragma unroll
    for (int r = 0; r < 4; ++r) {
        int n = n0 + wave * 16 + lg * 4 + r;
        hn[r] = n % HH;
        wn[r] = n / HH;
    }
    const float* rhq_b = rhq + (size_t)b * HH * NN;
    const float* rwq_b = rwq + (size_t)b * HH * NN;

    // PV ownership: [64n x 64c] per wave
    int nh = wave >> 2;                 // n-half: rows nh*64 .. +63
    int cq = wave & 3;                  // c-quarter: cols cq*64 .. +63
    f32x4 oacc[4][4] = {};              // [nf][cf]
    float mrun[4] = {-1e30f, -1e30f, -1e30f, -1e30f};
    float lrun[4] = {0.f, 0.f, 0.f, 0.f};

    // staging: LDS dest linear (lane*16B); global source chunk pre-swizzled so
    // logical chunk c of row r lands at physical chunk c^(r&7).
    int srl = lane >> 3;                      // row within wave's 8-row group
    int sch = ((lane & 7) ^ srl) * 8;         // pre-swizzled source offset (elems)
    auto STAGE_K = [&](int buf, int m0s, int k0) {
        int grow = m0s + wave * 8 + srl;
        gload_lds16(kt + (bN + grow) * CC + k0 + sch, &lds_k[buf][wave * 8][0]);
    };
    auto STAGE_V = [&](int q, int m0s) {       // quarter q: c-rows [q*64, q*64+64)
        int crow = q * 64 + wave * 8 + srl;
        gload_lds16(vbuf + ((size_t)b * CC + crow) * NN + m0s + sch, &lds_v[q * 64 + wave * 8][0]);
    };

    int cur = 0;
    STAGE_K(0, t0 * 64, 0);
    __syncthreads();

    for (int t = t0; t < t_end; ++t) {
        int m0 = t * 64;
        // pos adds (issued early; consumed after 4 phases — hidden)
        float padd[4][4];
        #pragma unroll
        for (int mt = 0; mt < 4; ++mt) {
            int m = m0 + mt * 16 + lr;
            #pragma unroll
            for (int r = 0; r < 4; ++r)
                padd[mt][r] = rhq_b[(size_t)hn[r] * NN + m] + rwq_b[(size_t)wn[r] * NN + m];
        }
        // ---- S tile [16n x 64m], K=256 in 4 phases of 64, f16 2-pass ----
        f32x4 sacc[4] = {};
        #pragma unroll
        for (int ph = 0; ph < 4; ++ph) {
            if (ph < 3) STAGE_K(cur ^ 1, m0, (ph + 1) * 64);
            else if (t + 1 < t_end) STAGE_K(cur ^ 1, m0 + 64, 0);
            STAGE_V(ph, m0);                       // quarter ph of current tile
            #pragma unroll
            for (int ks = 0; ks < 2; ++ks) {
                #pragma unroll
                for (int mt = 0; mt < 4; ++mt) {
                    int row = mt * 16 + lr;
                    int ch = ((ks * 4 + lg) ^ (lr & 7)) * 8;   // swizzled read
                    f16x8 bh = *reinterpret_cast<const f16x8*>(&lds_k[cur][row][ch]);
                    sacc[mt] = MFMAH(qh[ph * 2 + ks], bh, sacc[mt]);
                    sacc[mt] = MFMAH(ql[ph * 2 + ks], bh, sacc[mt]);
                }
            }
            __syncthreads();
            cur ^= 1;
        }
        // ---- add pos term, online softmax (per S-wave rows) ----
        #pragma unroll
        for (int mt = 0; mt < 4; ++mt)
            #pragma unroll
            for (int r = 0; r < 4; ++r)
                sacc[mt][r] += padd[mt][r];
        float scl_r[4];
        #pragma unroll
        for (int r = 0; r < 4; ++r) {
            float smax = fmaxf(fmaxf(sacc[0][r], sacc[1][r]), fmaxf(sacc[2][r], sacc[3][r]));
            #pragma unroll
            for (int mk = 1; mk <= 8; mk <<= 1)
                smax = fmaxf(smax, __shfl_xor(smax, mk));
            float mnew = fmaxf(mrun[r], smax);
            scl_r[r] = __expf(mrun[r] - mnew);
            float rsum = 0.f;
            #pragma unroll
            for (int mt = 0; mt < 4; ++mt) {
                float p = __expf(sacc[mt][r] - mnew);
                sacc[mt][r] = p;
                rsum += p;
            }
            #pragma unroll
            for (int mk = 1; mk <= 8; mk <<= 1)
                rsum += __shfl_xor(rsum, mk);
            lrun[r] = lrun[r] * scl_r[r] + rsum;
            mrun[r] = mnew;
        }
        // ---- P + scale -> shared LDS (XOR-swizzled P; scale into dead buf1)
        #pragma unroll
        for (int mt = 0; mt < 4; ++mt) {
            #pragma unroll
            for (int r = 0; r < 4; ++r) {
                int prow = wave * 16 + lg * 4 + r;
                int pcol = mt * 16 + lr;
                int pcol_s = (((pcol >> 3) ^ (prow & 7)) << 3) | (pcol & 7);
                lds_p[prow][pcol_s] = __float2bfloat16(sacc[mt][r]);
            }
        }
        if (lr == 0) {
            #pragma unroll
            for (int r = 0; r < 4; ++r)
                lds_scale[wave * 16 + lg * 4 + r] = scl_r[r];
        }
        __syncthreads();   // P, scale, and all 4 V quarters visible
        // ---- PV: wave computes [64n x 64c]; rescale then accumulate ----
        f32x4 scl4[4];
        #pragma unroll
        for (int nf = 0; nf < 4; ++nf) {
            scl4[nf] = *reinterpret_cast<const f32x4*>(&lds_scale[nh * 64 + nf * 16 + lg * 4]);
            #pragma unroll
            for (int cf = 0; cf < 4; ++cf)
                oacc[nf][cf] *= scl4[nf];
        }
        #pragma unroll
        for (int ks2 = 0; ks2 < 2; ++ks2) {
            bf16x8 pa[4];
            #pragma unroll
            for (int nf = 0; nf < 4; ++nf) {
                int prow = nh * 64 + nf * 16 + lr;
                int pch = ((ks2 * 4 + lg) ^ (lr & 7)) * 8;
                pa[nf] = *reinterpret_cast<const bf16x8*>(&lds_p[prow][pch]);
            }
            #pragma unroll
            for (int cf = 0; cf < 4; ++cf) {
                int vrow = cq * 64 + cf * 16 + lr;
                int vch = ((ks2 * 4 + lg) ^ (lr & 7)) * 8;
                bf16x8 bv = *reinterpret_cast<const bf16x8*>(&lds_v[vrow][vch]);
                #pragma unroll
                for (int nf = 0; nf < 4; ++nf)
                    oacc[nf][cf] = MFMA(pa[nf], bv, oacc[nf][cf]);
            }
        }
        __syncthreads();   // PV reads (incl. scale in buf1) done before restage
    }
    // ---- epilogue: store unnormalized partial o (bf16) and per-row (m,l) ----
    if (lr == 0) {
        #pragma unroll
        for (int r = 0; r < 4; ++r) {
            int n = n0 + wave * 16 + lg * 4 + r;
            ml[((size_t)z * BB + b) * NN + n] = make_float2(mrun[r], lrun[r]);
        }
    }
    #pragma unroll
    for (int nf = 0; nf < 4; ++nf) {
        int nbase = n0 + nh * 64 + nf * 16 + lg * 4;
        #pragma unroll
        for (int cf = 0; cf < 4; ++cf) {
            int c = cq * 64 + cf * 16 + lr;
            union { ushort4 u4; unsigned short us[4]; } pk;
            #pragma unroll
            for (int j = 0; j < 4; ++j) {
                __hip_bfloat16 hv = __float2bfloat16(oacc[nf][cf][j]);
                pk.us[j] = *reinterpret_cast<unsigned short*>(&hv);
            }
            *reinterpret_cast<ushort4*>(&opart[((size_t)b * CC + c) * NN + nbase]) = pk.u4;
        }
    }
}

// ---- combine: out[b][c][n] = sum_z o_z*exp(m_z-M) / sum_z l_z*exp(m_z-M) ----
__global__ __launch_bounds__(256) void k_combine(
        const __hip_bfloat16* __restrict__ o0, const __hip_bfloat16* __restrict__ o1,
        const __hip_bfloat16* __restrict__ o2, const __hip_bfloat16* __restrict__ o3,
        const float2* __restrict__ ml, int nsplit, float* __restrict__ out) {
    size_t idx = ((size_t)blockIdx.x * 256 + threadIdx.x) * 4;   // over B*CC*NN
    int n4 = (int)(idx % NN);
    int c  = (int)((idx / NN) % CC);
    int b  = (int)(idx / ((size_t)NN * CC));
    // pass 1: row maxes (no z-indexed register arrays — rule #20)
    float M[4] = {-1e30f, -1e30f, -1e30f, -1e30f};
    for (int zz = 0; zz < nsplit; ++zz) {
        #pragma unroll
        for (int j = 0; j < 4; ++j)
            M[j] = fmaxf(M[j], ml[((size_t)zz * BB + b) * NN + n4 + j].x);
    }
    // pass 2: weighted accumulate (ml reload is L2-hot, 1.2MB table)
    float num[4] = {}, den[4] = {};
    for (int zz = 0; zz < nsplit; ++zz) {
        const __hip_bfloat16* op = (zz == 0) ? o0 : (zz == 1) ? o1 : (zz == 2) ? o2 : o3;
        ushort4 u = *reinterpret_cast<const ushort4*>(op + ((size_t)b * CC + c) * NN + n4);
        unsigned short us[4] = {u.x, u.y, u.z, u.w};
        #pragma unroll
        for (int j = 0; j < 4; ++j) {
            float2 v = ml[((size_t)zz * BB + b) * NN + n4 + j];
            float w = __expf(v.x - M[j]);
            num[j] += bf2f(us[j]) * w;
            den[j] += v.y * w;
        }
    }
    f32x4 o;
    #pragma unroll
    for (int j = 0; j < 4; ++j) o[j] = num[j] / den[j];
    *reinterpret_cast<f32x4*>(&out[idx]) = o;
}

extern "C" void kernel_launch(void* const* d_in, const int* in_sizes, int n_in,
                              void* d_out, int out_size, void* d_ws, size_t ws_size,
                              hipStream_t stream) {
    const float* x     = (const float*)d_in[0];
    const float* Wq    = (const float*)d_in[1];
    const float* bq    = (const float*)d_in[2];
    const float* Wk    = (const float*)d_in[3];
    const float* bk    = (const float*)d_in[4];
    const float* Wv    = (const float*)d_in[5];
    const float* bv    = (const float*)d_in[6];
    const float* rel_h = (const float*)d_in[7];
    const float* rel_w = (const float*)d_in[8];
    float* out = (float*)d_out;

    size_t off = 0;
    auto carve = [&](size_t bytes) {
        void* p = (char*)d_ws + off;
        off += (bytes + 255) & ~(size_t)255;
        return p;
    };
    const size_t sz_t = (size_t)BB * NN * CC * 2;   // one 2B plane = 18.87 MB
    __hip_bfloat16* xt_hi  = (__hip_bfloat16*)carve(sz_t);
    __hip_bfloat16* xt_lo  = (__hip_bfloat16*)carve(sz_t);
    _Float16*       qt_hi  = (_Float16*)carve(sz_t);
    _Float16*       qt_lo  = (_Float16*)carve(sz_t);
    _Float16*       kt     = (_Float16*)carve(sz_t);
    __hip_bfloat16* vbuf   = (__hip_bfloat16*)carve(sz_t);
    _Float16* relhT_hi = (_Float16*)carve((size_t)HH * CC * 2);
    _Float16* relhT_lo = (_Float16*)carve((size_t)HH * CC * 2);
    _Float16* relwT_hi = (_Float16*)carve((size_t)HH * CC * 2);
    _Float16* relwT_lo = (_Float16*)carve((size_t)HH * CC * 2);
    __hip_bfloat16* w_hi   = (__hip_bfloat16*)carve((size_t)3 * CC * CC * 2);
    __hip_bfloat16* w_lo   = (__hip_bfloat16*)carve((size_t)3 * CC * CC * 2);
    float* rhq = (float*)carve((size_t)BB * HH * NN * 4);
    float* rwq = (float*)carve((size_t)BB * HH * NN * 4);
    float2* ml = (float2*)carve((size_t)4 * BB * NN * sizeof(float2));
    if (off > ws_size) return;   // base workspace too small -> visible failure

    // split-KV partial planes: 0/1 alias dead xt_hi/xt_lo; 2/3 only if ws fits
    __hip_bfloat16* o0 = xt_hi;
    __hip_bfloat16* o1 = xt_lo;
    __hip_bfloat16* o2 = nullptr;
    __hip_bfloat16* o3 = nullptr;
    int nsplit = 2;
    {
        size_t save = off;
        __hip_bfloat16* p2 = (__hip_bfloat16*)carve(sz_t);
        __hip_bfloat16* p3 = (__hip_bfloat16*)carve(sz_t);
        if (off <= ws_size) { nsplit = 4; o2 = p2; o3 = p3; }
        else { off = save; }
    }
    int tpb = 36 / nsplit;

    k_prep_x<<<dim3(NN / 64, CC / 64, BB), 256, 0, stream>>>(x, xt_hi, xt_lo);
    k_prep_w<<<dim3(3 * CC * CC / 256), 256, 0, stream>>>(Wq, Wk, Wv, w_hi, w_lo);
    k_prep_rel<<<dim3(HH * CC / 256), 256, 0, stream>>>(rel_h, rel_w,
        relhT_hi, relhT_lo, relwT_hi, relwT_lo);
    k_proj<<<dim3((NN / 64) * (CC / 64), BB, 3), 256, 0, stream>>>(
        xt_hi, xt_lo, w_hi, w_lo, bq, bk, bv, qt_hi, qt_lo, kt, vbuf);
    k_posq<<<dim3(NN / 64, BB), 256, 0, stream>>>(
        qt_hi, qt_lo, relhT_hi, relhT_lo, relwT_hi, relwT_lo, rhq, rwq);
    k_attn<<<dim3(NN / 128, BB, nsplit), 512, 0, stream>>>(
        qt_hi, qt_lo, kt, rhq, rwq, vbuf, o0, o1, o2, o3, ml, tpb);
    k_combine<<<dim3((size_t)BB * CC * NN / 1024), 256, 0, stream>>>(
        o0, o1, o2, o3, ml, nsplit, out);
}